// Round 8
// baseline (201.011 us; speedup 1.0000x reference)
//
#include <hip/hip_runtime.h>
#include <hip/hip_bf16.h>
#include <math.h>

// Problem constants
#define NPIX   25600      // H*W = 160*160
#define CDIM   256
#define SSEL   1024       // MAX_SAMPLES
#define BATCH  4
#define NCHUNK 25         // NPIX / 1024
#define INV_T  10.0f      // 1/TEMP
#define RATIO  1.4285714285714286f  // TEMP/BASE_TEMP
#define THR    0.7f

typedef __attribute__((ext_vector_type(8))) short bf16x8;
typedef __attribute__((ext_vector_type(4))) float f32x4;
typedef unsigned short u16;

__device__ __forceinline__ u16 to_bf16(float v) {
  __hip_bfloat16 h = __float2bfloat16(v);
  return *reinterpret_cast<u16*>(&h);
}

// ---------------------------------------------------------------------------
// Kernel 0: weights fp32 -> bf16 ([out][in] row-major) + zero accumulators +
// per-chunk valid counts.
// ---------------------------------------------------------------------------
__global__ __launch_bounds__(256) void pack_weights(
    const float* __restrict__ w1, const float* __restrict__ w2,
    const float* __restrict__ wa1, const int* __restrict__ labels,
    u16* __restrict__ w1b, u16* __restrict__ w2b, u16* __restrict__ wab,
    float* __restrict__ denom, float* __restrict__ Prow, float* __restrict__ Ssum,
    int* __restrict__ counts) {
  int t = threadIdx.x;
  int e = blockIdx.x * 256 + t;
  if (e < 65536) {
    w1b[e] = to_bf16(w1[e]);
    w2b[e] = to_bf16(w2[e]);
  }
  if (e < 16384) wab[e] = to_bf16(wa1[e]);
  if (e < BATCH * SSEL) { denom[e] = 0.f; Prow[e] = 0.f; }
  if (e < BATCH) Ssum[e] = 0.f;

  if (blockIdx.x < BATCH * NCHUNK) {
    int b = blockIdx.x / NCHUNK, ch = blockIdx.x % NCHUNK;
    const int* lab = labels + b * NPIX + ch * 1024;
    int local = 0;
#pragma unroll
    for (int qq = 0; qq < 4; ++qq) local += (lab[qq * 256 + t] == 1);
    for (int off = 32; off > 0; off >>= 1) local += __shfl_xor(local, off, 64);
    __shared__ int ws[4];
    if ((t & 63) == 0) ws[t >> 6] = local;
    __syncthreads();
    if (t == 0) counts[blockIdx.x] = ws[0] + ws[1] + ws[2] + ws[3];
  }
}

// ---------------------------------------------------------------------------
// Kernel 1: stable scatter ("valid first" order, first 1024 slots).
// ---------------------------------------------------------------------------
__global__ __launch_bounds__(1024) void select_scatter(
    const int* __restrict__ labels, const int* __restrict__ sp,
    const int* __restrict__ counts,
    int* __restrict__ idx, int* __restrict__ selv, int* __restrict__ tsp) {
  int b = blockIdx.x / NCHUNK, ch = blockIdx.x % NCHUNK;
  int t = threadIdx.x;
  __shared__ int cs[NCHUNK];
  __shared__ int wave_tot[16];
  if (t < NCHUNK) cs[t] = counts[b * NCHUNK + t];
  __syncthreads();
  int Vtot = 0, vbase = 0;
#pragma unroll
  for (int c = 0; c < NCHUNK; ++c) {
    int v = cs[c];
    Vtot += v;
    if (c < ch) vbase += v;
  }
  int ibase = ch * 1024 - vbase;

  int i = ch * 1024 + t;
  int isv = (labels[b * NPIX + i] == 1) ? 1 : 0;
  int lane = t & 63, wid = t >> 6;
  unsigned long long mv = __ballot(isv);
  int pv = __popcll(mv & ((1ull << lane) - 1ull));
  if (lane == 0) wave_tot[wid] = __popcll(mv);
  __syncthreads();
  for (int w = 0; w < wid; ++w) pv += wave_tot[w];
  int gslot = isv ? (vbase + pv) : (Vtot + ibase + (t - pv));
  if (gslot < SSEL) {
    idx [b * SSEL + gslot] = i;
    selv[b * SSEL + gslot] = isv;
    tsp [b * SSEL + gslot] = sp[b * NPIX + i];
  }
}

// ---------------------------------------------------------------------------
// Kernel 2: gather selected pixels -> packed bf16 x [4096 x 256].
// Grid 1024 (4 rows/block) for latency hiding; thread = channel.
// ---------------------------------------------------------------------------
__global__ __launch_bounds__(256) void gather_cast(
    const float* __restrict__ feats, const int* __restrict__ idx,
    u16* __restrict__ xh) {
  int r0 = blockIdx.x * 4;
  int b  = r0 >> 10;
  int t  = threadIdx.x;
  __shared__ int ridx[4];
  if (t < 4) ridx[t] = idx[r0 + t];
  __syncthreads();
  const float* fb = feats + ((long)b * CDIM + t) * NPIX;
#pragma unroll
  for (int r = 0; r < 4; ++r) {
    xh[(long)(r0 + r) * CDIM + t] = to_bf16(fb[ridx[r]]);
  }
}

// ---------------------------------------------------------------------------
// Kernel 3: layer1 GEMM (bf16 MFMA, no LDS — fragments streamed from L2):
// h = relu(x @ w1.T + b1) -> bf16. Col-tile n==4 is the fused attn head -> tw.
// Grid (5, 64); 4 waves, wave = 16 rows x 64 cols, no barriers.
// ---------------------------------------------------------------------------
__global__ __launch_bounds__(256) void gemm1_kernel(
    const u16* __restrict__ xh, const u16* __restrict__ w1b,
    const u16* __restrict__ wab,
    const float* __restrict__ b1, const float* __restrict__ ba1,
    const float* __restrict__ wa2, const float* __restrict__ ba2,
    u16* __restrict__ hh, float* __restrict__ tw) {
  int n  = blockIdx.x;          // 0..3 = w1 col tiles, 4 = attn
  int i0 = blockIdx.y * 64;
  int t = threadIdx.x;
  int lane = t & 63, w = t >> 6, m = lane & 15, q = lane >> 4;
  bool attn = (n == 4);
  const u16* bsrc = attn ? wab : (w1b + n * 64 * 256);

  const u16* arow = xh + (i0 + w * 16 + m) * 256 + q * 8;
  const u16* brow = bsrc + m * 256 + q * 8;

  f32x4 acc[4];
#pragma unroll
  for (int nt = 0; nt < 4; ++nt) acc[nt] = {0.f, 0.f, 0.f, 0.f};

#pragma unroll
  for (int ks = 0; ks < 8; ++ks) {
    bf16x8 ah = *(const bf16x8*)&arow[ks * 32];
#pragma unroll
    for (int nt = 0; nt < 4; ++nt) {
      bf16x8 bh = *(const bf16x8*)&brow[nt * 16 * 256 + ks * 32];
      acc[nt] = __builtin_amdgcn_mfma_f32_16x16x32_bf16(ah, bh, acc[nt], 0, 0, 0);
    }
  }

  // C/D layout: col = lane&15 (m), row = q*4 + reg
  if (!attn) {
#pragma unroll
    for (int nt = 0; nt < 4; ++nt) {
      int col = n * 64 + nt * 16 + m;
      float bb = b1[col];
#pragma unroll
      for (int reg = 0; reg < 4; ++reg) {
        int row = i0 + w * 16 + q * 4 + reg;
        hh[row * 256 + col] = to_bf16(fmaxf(acc[nt][reg] + bb, 0.f));
      }
    }
  } else {
    float part[4] = {0.f, 0.f, 0.f, 0.f};
#pragma unroll
    for (int nt = 0; nt < 4; ++nt) {
      int ca = nt * 16 + m;
      float bb = ba1[ca], wv = wa2[ca];
#pragma unroll
      for (int reg = 0; reg < 4; ++reg)
        part[reg] += fmaxf(acc[nt][reg] + bb, 0.f) * wv;
    }
    for (int off = 8; off > 0; off >>= 1) {
#pragma unroll
      for (int reg = 0; reg < 4; ++reg)
        part[reg] += __shfl_xor(part[reg], off, 64);
    }
    if (m == 0) {
      float bb2 = ba2[0];
#pragma unroll
      for (int reg = 0; reg < 4; ++reg) {
        int row = i0 + w * 16 + q * 4 + reg;
        tw[row] = 1.f / (1.f + expf(-(part[reg] + bb2)));
      }
    }
  }
}

// ---------------------------------------------------------------------------
// Kernel 4: layer2 GEMM + row-norm fused (no LDS staging): p = h@w2.T + b2,
// fn = p/|p| -> bf16. Grid 256: block = 16 rows; wave w = col-tile w (64 cols).
// One barrier for the cross-wave norm reduction.
// ---------------------------------------------------------------------------
__global__ __launch_bounds__(256) void gemm2norm_kernel(
    const u16* __restrict__ hh, const u16* __restrict__ w2b,
    const float* __restrict__ b2, u16* __restrict__ fnb) {
  int i0 = blockIdx.x * 16;
  int t = threadIdx.x;
  int lane = t & 63, w = t >> 6, m = lane & 15, q = lane >> 4;

  const u16* arow = hh + (i0 + m) * 256 + q * 8;
  const u16* brow = w2b + (w * 64 + m) * 256 + q * 8;

  f32x4 acc[4];
#pragma unroll
  for (int nt = 0; nt < 4; ++nt) acc[nt] = {0.f, 0.f, 0.f, 0.f};

#pragma unroll
  for (int ks = 0; ks < 8; ++ks) {
    bf16x8 ah = *(const bf16x8*)&arow[ks * 32];
#pragma unroll
    for (int nt = 0; nt < 4; ++nt) {
      bf16x8 bh = *(const bf16x8*)&brow[nt * 16 * 256 + ks * 32];
      acc[nt] = __builtin_amdgcn_mfma_f32_16x16x32_bf16(ah, bh, acc[nt], 0, 0, 0);
    }
  }

  // bias + per-row partial sum-of-squares over this wave's 64 cols
  float ss[4] = {0.f, 0.f, 0.f, 0.f};
#pragma unroll
  for (int nt = 0; nt < 4; ++nt) {
    float bb = b2[w * 64 + nt * 16 + m];
#pragma unroll
    for (int reg = 0; reg < 4; ++reg) {
      float p = acc[nt][reg] + bb;
      acc[nt][reg] = p;
      ss[reg] += p * p;
    }
  }
  for (int off = 8; off > 0; off >>= 1) {
#pragma unroll
    for (int reg = 0; reg < 4; ++reg) ss[reg] += __shfl_xor(ss[reg], off, 64);
  }
  __shared__ float ssw[4][16];
  if (m == 0) {
#pragma unroll
    for (int reg = 0; reg < 4; ++reg) ssw[w][q * 4 + reg] = ss[reg];
  }
  __syncthreads();
#pragma unroll
  for (int nt = 0; nt < 4; ++nt) {
    int col = w * 64 + nt * 16 + m;
#pragma unroll
    for (int reg = 0; reg < 4; ++reg) {
      int r = q * 4 + reg;
      float tot = ssw[0][r] + ssw[1][r] + ssw[2][r] + ssw[3][r];
      float inv = 1.f / fmaxf(sqrtf(tot), 1e-12f);
      fnb[(i0 + r) * 256 + col] = to_bf16(acc[nt][reg] * inv);
    }
  }
}

// ---------------------------------------------------------------------------
// Kernel 5: MFMA sim = fn @ fn.T (bf16, no LDS staging — L2 streams).
// Triangular tiles tj>=ti; 64x64 per block, 4 waves, no K-loop barriers.
// ---------------------------------------------------------------------------
__global__ __launch_bounds__(256) void sim_kernel(
    const u16* __restrict__ fnb, const float* __restrict__ tw,
    const int* __restrict__ selv, const int* __restrict__ tsp,
    float* __restrict__ denom, float* __restrict__ Prow, float* __restrict__ Ssum) {
  int b = blockIdx.y;
  int t = threadIdx.x;
  int lane = t & 63, w = t >> 6;
  int m = lane & 15, q = lane >> 4;

  int rem = blockIdx.x, ti = 0;
  while (rem >= (16 - ti)) { rem -= (16 - ti); ++ti; }
  int tj = ti + rem;
  int i0 = ti * 64, j0 = tj * 64;
  int base = b << 10;

  __shared__ float drl[64], Prl[64];
  __shared__ float dclw[4][64], Pclw[4][64];
  __shared__ float swv[4];

  const u16* arow = fnb + (base + i0 + w * 16 + m) * 256 + q * 8;
  const u16* brow = fnb + (base + j0 + m) * 256 + q * 8;

  f32x4 acc[4];
#pragma unroll
  for (int nt = 0; nt < 4; ++nt) acc[nt] = {0.f, 0.f, 0.f, 0.f};

#pragma unroll
  for (int ks = 0; ks < 8; ++ks) {
    bf16x8 ah = *(const bf16x8*)&arow[ks * 32];
#pragma unroll
    for (int nt = 0; nt < 4; ++nt) {
      bf16x8 bh = *(const bf16x8*)&brow[nt * 16 * 256 + ks * 32];
      acc[nt] = __builtin_amdgcn_mfma_f32_16x16x32_bf16(ah, bh, acc[nt], 0, 0, 0);
    }
  }

  bool diag = (ti == tj);
  int   gi[4], gj[4], si[4], sj[4], ci[4], cj[4];
  float twi[4], twj[4];
#pragma unroll
  for (int reg = 0; reg < 4; ++reg) {
    int i = i0 + w * 16 + q * 4 + reg;
    gi[reg] = i; twi[reg] = tw[base + i];
    si[reg] = selv[base + i]; ci[reg] = tsp[base + i];
  }
#pragma unroll
  for (int nt = 0; nt < 4; ++nt) {
    int j = j0 + nt * 16 + m;
    gj[nt] = j; twj[nt] = tw[base + j];
    sj[nt] = selv[base + j]; cj[nt] = tsp[base + j];
  }

  float dR[4] = {0, 0, 0, 0}, PR[4] = {0, 0, 0, 0};
  float dC[4] = {0, 0, 0, 0}, PC[4] = {0, 0, 0, 0};
  float Sp = 0.f;
#pragma unroll
  for (int nt = 0; nt < 4; ++nt) {
#pragma unroll
    for (int reg = 0; reg < 4; ++reg) {
      float s = acc[nt][reg];
      float e10 = __expf(s * INV_T);
      if (sj[nt]) dR[reg] += e10;
      if (si[reg]) dC[nt] += e10;
      if (si[reg] && sj[nt] && (ci[reg] == cj[nt]) && (s > THR) && (gi[reg] != gj[nt])) {
        float pw = twi[reg] * twj[nt];
        PR[reg] += pw;
        PC[nt] += pw;
        Sp += pw * s;
      }
    }
  }

  for (int off = 8; off > 0; off >>= 1) {
#pragma unroll
    for (int reg = 0; reg < 4; ++reg) {
      dR[reg] += __shfl_xor(dR[reg], off, 64);
      PR[reg] += __shfl_xor(PR[reg], off, 64);
    }
  }
  if (m == 0) {
#pragma unroll
    for (int reg = 0; reg < 4; ++reg) {
      drl[w * 16 + q * 4 + reg] = dR[reg];
      Prl[w * 16 + q * 4 + reg] = PR[reg];
    }
  }
  if (!diag) {
    for (int off = 32; off >= 16; off >>= 1) {
#pragma unroll
      for (int nt = 0; nt < 4; ++nt) {
        dC[nt] += __shfl_xor(dC[nt], off, 64);
        PC[nt] += __shfl_xor(PC[nt], off, 64);
      }
    }
    if (q == 0) {
#pragma unroll
      for (int nt = 0; nt < 4; ++nt) {
        dclw[w][nt * 16 + m] = dC[nt];
        Pclw[w][nt * 16 + m] = PC[nt];
      }
    }
  }
  for (int off = 32; off > 0; off >>= 1) Sp += __shfl_xor(Sp, off, 64);
  if (lane == 0) swv[w] = Sp;
  __syncthreads();

  if (t < 64) {
    atomicAdd(&denom[base + i0 + t], drl[t]);
    atomicAdd(&Prow [base + i0 + t], Prl[t]);
    if (!diag) {
      float dc = dclw[0][t] + dclw[1][t] + dclw[2][t] + dclw[3][t];
      float pc = Pclw[0][t] + Pclw[1][t] + Pclw[2][t] + Pclw[3][t];
      atomicAdd(&denom[base + j0 + t], dc);
      atomicAdd(&Prow [base + j0 + t], pc);
    }
  }
  if (t == 0) {
    float St = swv[0] + swv[1] + swv[2] + swv[3];
    atomicAdd(&Ssum[b], diag ? St : 2.f * St);
  }
}

// ---------------------------------------------------------------------------
// Kernel 6: finalize. loss_b = -(T/BT) * (S_b/T - sum_i P_i log D_i) / psum_b
// ---------------------------------------------------------------------------
__global__ __launch_bounds__(1024) void finalize_kernel(
    const float* __restrict__ denom, const float* __restrict__ Prow,
    const float* __restrict__ Ssum, float* __restrict__ out) {
  int t = threadIdx.x;
  int b = t >> 8, u = t & 255;
  float P = 0.f, L = 0.f;
#pragma unroll
  for (int q = 0; q < 4; ++q) {
    int s = u + q * 256;
    float p = Prow[b * SSEL + s];
    float D = denom[b * SSEL + s];
    P += p;
    L += p * logf(D > 0.f ? D : 1.f);
  }
  for (int off = 32; off > 0; off >>= 1) {
    P += __shfl_xor(P, off, 64);
    L += __shfl_xor(L, off, 64);
  }
  __shared__ float wP[16], wL[16];
  int lane = t & 63, w = t >> 6;
  if (lane == 0) { wP[w] = P; wL[w] = L; }
  __syncthreads();
  if (t == 0) {
    float total = 0.f, n = 0.f;
    for (int bb = 0; bb < BATCH; ++bb) {
      float psum = wP[4 * bb] + wP[4 * bb + 1] + wP[4 * bb + 2] + wP[4 * bb + 3];
      float lsum = wL[4 * bb] + wL[4 * bb + 1] + wL[4 * bb + 2] + wL[4 * bb + 3];
      if (psum > 0.f) {
        float wls = Ssum[bb] * INV_T - lsum;
        total += -RATIO * wls / psum;
        n += 1.f;
      }
    }
    out[0] = (n > 0.f) ? (total / n) : 0.f;
  }
}

// ---------------------------------------------------------------------------
extern "C" void kernel_launch(void* const* d_in, const int* in_sizes, int n_in,
                              void* d_out, int out_size, void* d_ws, size_t ws_size,
                              hipStream_t stream) {
  const float* feats = (const float*)d_in[0];
  const int*   labels = (const int*)d_in[1];
  const int*   sp     = (const int*)d_in[2];
  const float* w1  = (const float*)d_in[3];
  const float* b1  = (const float*)d_in[4];
  const float* w2  = (const float*)d_in[5];
  const float* b2  = (const float*)d_in[6];
  const float* wa1 = (const float*)d_in[7];
  const float* ba1 = (const float*)d_in[8];
  const float* wa2 = (const float*)d_in[9];
  const float* ba2 = (const float*)d_in[10];
  float* out = (float*)d_out;

  char* W = (char*)d_ws;
  u16* w1b = (u16*)W;               W += 65536 * 2;
  u16* w2b = (u16*)W;               W += 65536 * 2;
  u16* wab = (u16*)W;               W += 16384 * 2;
  u16* xh  = (u16*)W;               W += 1048576 * 2;
  u16* hh  = (u16*)W;               W += 1048576 * 2;
  u16* fnb = (u16*)W;               W += 1048576 * 2;
  float* tw   = (float*)W;          W += 4096 * 4;
  float* denom= (float*)W;          W += 4096 * 4;
  float* Prow = (float*)W;          W += 4096 * 4;
  float* Ssum = (float*)W;          W += 4 * 4;
  int*   idx  = (int*)W;            W += 4096 * 4;
  int*   selv = (int*)W;            W += 4096 * 4;
  int*   tsp  = (int*)W;            W += 4096 * 4;
  int*   counts = (int*)W;          W += 128 * 4;

  pack_weights<<<256, 256, 0, stream>>>(w1, w2, wa1, labels, w1b, w2b, wab,
                                        denom, Prow, Ssum, counts);
  select_scatter<<<BATCH * NCHUNK, 1024, 0, stream>>>(labels, sp, counts,
                                                      idx, selv, tsp);
  gather_cast<<<1024, 256, 0, stream>>>(feats, idx, xh);
  gemm1_kernel<<<dim3(5, 64), 256, 0, stream>>>(xh, w1b, wab, b1, ba1,
                                                wa2, ba2, hh, tw);
  gemm2norm_kernel<<<256, 256, 0, stream>>>(hh, w2b, b2, fnb);
  sim_kernel<<<dim3(136, BATCH), 256, 0, stream>>>(fnb, tw, selv, tsp,
                                                   denom, Prow, Ssum);
  finalize_kernel<<<1, 1024, 0, stream>>>(denom, Prow, Ssum, out);
}